// Round 5
// baseline (585.345 us; speedup 1.0000x reference)
//
#include <hip/hip_runtime.h>
#include <hip/hip_bf16.h>

// 3-layer tanh RNN. B=32, T=64, D_IN=10000, H=200, N_CLASSES=2.
// GEMMs: split-bf16 MFMA (v = hi+lo; A*B ~= Ah*Bh + Ah*Bl + Al*Bh -> ~fp32),
// register-prefetch pipelined, 2 blocks/CU. LDS_K=56 (112B row stride:
// 16B-aligned ds_*_b128 everywhere -- LDS_K=40 misalignment was the R1/R2 bug).
// rec: per-batch pre slab staged in LDS once; 4-way split accumulator chain.

typedef __bf16  bf16x8 __attribute__((ext_vector_type(8)));
typedef float   f32x4  __attribute__((ext_vector_type(4)));

#define HDIM 200
#define BM 128
#define BN 208      // 13 * 16 (N=200 padded)
#define BK 32
#define LDS_K 56    // 32 + 24 pad: 112B row stride, 16B-aligned everywhere

__device__ __forceinline__ void split_bf16(const float* v, bf16x8* hi, bf16x8* lo) {
#pragma unroll
    for (int i = 0; i < 8; ++i) {
        __bf16 h = (__bf16)v[i];
        (*hi)[i] = h;
        (*lo)[i] = (__bf16)(v[i] - (float)h);
    }
}

// C[m][n] (+)= sum_k A[m][k] * B[n][k]   (NT-GEMM; B row-major [n][k])
// 8 waves = 4 M-groups (32 rows) x 2 N-groups (7/6 nt tiles).
// accumulate=1: atomicAdd into pre-zeroed C. 0: plain store.
__global__ __launch_bounds__(512, 1)
void gemm_nt_bf16c(const float* __restrict__ A, int lda,
                   const float* __restrict__ B, int ldb,
                   float* __restrict__ C, int Ncols,
                   int K, int ksteps, int accumulate)
{
    __shared__ alignas(16) __bf16 Ash[BM * LDS_K];
    __shared__ alignas(16) __bf16 Asl[BM * LDS_K];
    __shared__ alignas(16) __bf16 Bsh[BN * LDS_K];
    __shared__ alignas(16) __bf16 Bsl[BN * LDS_K];

    const int tid   = threadIdx.x;
    const int m0    = blockIdx.x * BM;
    const int kbase = blockIdx.y * (ksteps * BK);
    const int wv    = tid >> 6;
    const int lane  = tid & 63;
    const int row16 = lane & 15;
    const int kg    = lane >> 4;      // 0..3
    const int mwv   = wv & 3;         // M-group: rows [mwv*32, mwv*32+32)
    const int nwv   = wv >> 2;        // N-group
    const int nt0   = nwv * 7;        // 0 or 7
    const int ntw   = nwv ? 6 : 7;

    f32x4 acc[2][7];
#pragma unroll
    for (int mi = 0; mi < 2; ++mi)
#pragma unroll
        for (int j = 0; j < 7; ++j) acc[mi][j] = (f32x4)0.f;

    // staging geometry
    const int a_row = tid >> 2;            // 0..127
    const int a_c8  = (tid & 3) * 8;       // 0,8,16,24
    const int u1    = tid + 512;           // B chunk 1
    const int b_r1  = u1 >> 2;             // 128..207 (tid<320)
    const int b_c1  = (u1 & 3) * 8;
    const bool has_b1 = (u1 < BN * 4);

    float av[8], bv0[8], bv1[8];

    auto load_tile = [&](int k0) {
        {   // A rows 0..127 (M=2048 multiple of 128; K multiple of 8)
            const int k = k0 + a_c8;
            if (k < K) {
                const float* p = A + (size_t)(m0 + a_row) * lda + k;
                float4 x0 = *(const float4*)p, x1 = *(const float4*)(p + 4);
                av[0]=x0.x; av[1]=x0.y; av[2]=x0.z; av[3]=x0.w;
                av[4]=x1.x; av[5]=x1.y; av[6]=x1.z; av[7]=x1.w;
            } else {
#pragma unroll
                for (int i = 0; i < 8; ++i) av[i] = 0.f;
            }
        }
        {   // B rows 0..127 (always < Ncols=200)
            const int k = k0 + a_c8;
            if (k < K) {
                const float* p = B + (size_t)a_row * ldb + k;
                float4 x0 = *(const float4*)p, x1 = *(const float4*)(p + 4);
                bv0[0]=x0.x; bv0[1]=x0.y; bv0[2]=x0.z; bv0[3]=x0.w;
                bv0[4]=x1.x; bv0[5]=x1.y; bv0[6]=x1.z; bv0[7]=x1.w;
            } else {
#pragma unroll
                for (int i = 0; i < 8; ++i) bv0[i] = 0.f;
            }
        }
        if (has_b1) {   // B rows 128..207 (guard r < Ncols)
            const int k = k0 + b_c1;
            if (b_r1 < Ncols && k < K) {
                const float* p = B + (size_t)b_r1 * ldb + k;
                float4 x0 = *(const float4*)p, x1 = *(const float4*)(p + 4);
                bv1[0]=x0.x; bv1[1]=x0.y; bv1[2]=x0.z; bv1[3]=x0.w;
                bv1[4]=x1.x; bv1[5]=x1.y; bv1[6]=x1.z; bv1[7]=x1.w;
            } else {
#pragma unroll
                for (int i = 0; i < 8; ++i) bv1[i] = 0.f;
            }
        }
    };

    load_tile(kbase);

    for (int ks = 0; ks < ksteps; ++ks) {
        // ---- commit prefetched regs to LDS ----
        bf16x8 th, tl;
        split_bf16(av, &th, &tl);
        *(bf16x8*)&Ash[a_row * LDS_K + a_c8] = th;
        *(bf16x8*)&Asl[a_row * LDS_K + a_c8] = tl;
        split_bf16(bv0, &th, &tl);
        *(bf16x8*)&Bsh[a_row * LDS_K + a_c8] = th;
        *(bf16x8*)&Bsl[a_row * LDS_K + a_c8] = tl;
        if (has_b1) {
            split_bf16(bv1, &th, &tl);
            *(bf16x8*)&Bsh[b_r1 * LDS_K + b_c1] = th;
            *(bf16x8*)&Bsl[b_r1 * LDS_K + b_c1] = tl;
        }
        __syncthreads();

        // ---- prefetch next tile (hidden under MFMA below) ----
        if (ks + 1 < ksteps) load_tile(kbase + (ks + 1) * BK);

        // ---- compute tile ks from LDS ----
        const int ar0 = (mwv * 32 + row16) * LDS_K + kg * 8;
        const int ar1 = ar0 + 16 * LDS_K;
        bf16x8 ah0 = *(const bf16x8*)&Ash[ar0];
        bf16x8 al0 = *(const bf16x8*)&Asl[ar0];
        bf16x8 ah1 = *(const bf16x8*)&Ash[ar1];
        bf16x8 al1 = *(const bf16x8*)&Asl[ar1];
#pragma unroll
        for (int j = 0; j < 7; ++j) {
            if (j < ntw) {
                const int off = ((nt0 + j) * 16 + row16) * LDS_K + kg * 8;
                bf16x8 bh = *(const bf16x8*)&Bsh[off];
                bf16x8 bl = *(const bf16x8*)&Bsl[off];
                acc[0][j] = __builtin_amdgcn_mfma_f32_16x16x32_bf16(al0, bh, acc[0][j], 0, 0, 0);
                acc[0][j] = __builtin_amdgcn_mfma_f32_16x16x32_bf16(ah0, bl, acc[0][j], 0, 0, 0);
                acc[0][j] = __builtin_amdgcn_mfma_f32_16x16x32_bf16(ah0, bh, acc[0][j], 0, 0, 0);
                acc[1][j] = __builtin_amdgcn_mfma_f32_16x16x32_bf16(al1, bh, acc[1][j], 0, 0, 0);
                acc[1][j] = __builtin_amdgcn_mfma_f32_16x16x32_bf16(ah1, bl, acc[1][j], 0, 0, 0);
                acc[1][j] = __builtin_amdgcn_mfma_f32_16x16x32_bf16(ah1, bh, acc[1][j], 0, 0, 0);
            }
        }
        __syncthreads();
    }

    // ---- epilogue: C/D layout col=lane&15, row=(lane>>4)*4+reg ----
#pragma unroll
    for (int mi = 0; mi < 2; ++mi) {
        const int rbase = m0 + mwv * 32 + mi * 16 + kg * 4;
#pragma unroll
        for (int j = 0; j < 7; ++j) {
            if (j < ntw) {
                const int n = (nt0 + j) * 16 + row16;
                if (n < Ncols) {
                    if (accumulate) {
#pragma unroll
                        for (int r = 0; r < 4; ++r)
                            atomicAdd(&C[(size_t)(rbase + r) * Ncols + n], acc[mi][j][r]);
                    } else {
#pragma unroll
                        for (int r = 0; r < 4; ++r)
                            C[(size_t)(rbase + r) * Ncols + n] = acc[mi][j][r];
                    }
                }
            }
        }
    }
}

// One workgroup per batch element. W_hh row j in thread j's VGPRs.
// pre slab staged in LDS once (no global loads in the sequential loop);
// 4 independent accumulators break the FMA dependence chain.
__global__ __launch_bounds__(256, 1)
void rnn_rec(const float* __restrict__ pre,   // [32][64][200] (GEMM only)
             const float* __restrict__ Whh,   // [200][200]
             const float* __restrict__ bih,
             const float* __restrict__ bhh,
             float* __restrict__ Hout)        // [32][64][200]
{
    const int b   = blockIdx.x;
    const int tid = threadIdx.x;

    __shared__ float preS[64 * HDIM];    // 51.2 KB
    __shared__ float h[2][HDIM];
    __shared__ float bias[HDIM];

    {   // coalesced preload: 3200 float4
        const float4* ps = (const float4*)(pre + (size_t)b * 64 * HDIM);
        float4* pd = (float4*)preS;
        for (int i = tid; i < 3200; i += 256) pd[i] = ps[i];
    }

    float w[HDIM];
    if (tid < HDIM) {
        const float* wr = Whh + (size_t)tid * HDIM;
#pragma unroll
        for (int i = 0; i < 50; ++i) {
            float4 v = *(const float4*)(wr + i * 4);
            w[i * 4 + 0] = v.x; w[i * 4 + 1] = v.y;
            w[i * 4 + 2] = v.z; w[i * 4 + 3] = v.w;
        }
        bias[tid] = bih[tid] + bhh[tid];
        h[0][tid] = 0.f;
    }
    __syncthreads();

    for (int t = 0; t < 64; ++t) {
        const float* hc = h[t & 1];
        float a0 = 0.f, a1 = 0.f, a2 = 0.f, a3 = 0.f;
#pragma unroll
        for (int k4 = 0; k4 < 50; ++k4) {
            float4 hv = *(const float4*)&hc[k4 * 4];   // wave-uniform broadcast
            a0 += w[k4 * 4 + 0] * hv.x;
            a1 += w[k4 * 4 + 1] * hv.y;
            a2 += w[k4 * 4 + 2] * hv.z;
            a3 += w[k4 * 4 + 3] * hv.w;
        }
        if (tid < HDIM) {
            float v = tanhf((a0 + a1) + (a2 + a3) + preS[t * HDIM + tid] + bias[tid]);
            h[(t + 1) & 1][tid] = v;
            Hout[((size_t)b * 64 + t) * HDIM + tid] = v;
        }
        __syncthreads();
    }
}

// Trivially-correct FC: one thread per logit, serial 200-length dot.
__global__ void fc_head(const float* __restrict__ Hlast_base, // [32][64][200]
                        const float* __restrict__ fcw,        // [2][200]
                        const float* __restrict__ fcb,        // [2]
                        float* __restrict__ out)              // [32][2]
{
    const int i = threadIdx.x;   // 0..63
    if (i >= 64) return;
    const int b   = i >> 1;
    const int cls = i & 1;
    const float* hp = Hlast_base + ((size_t)b * 64 + 63) * HDIM;
    const float* fw = fcw + cls * HDIM;
    float s = fcb[cls];
    for (int j = 0; j < HDIM; ++j) s += hp[j] * fw[j];
    out[b * 2 + cls] = s;
}

extern "C" void kernel_launch(void* const* d_in, const int* in_sizes, int n_in,
                              void* d_out, int out_size, void* d_ws, size_t ws_size,
                              hipStream_t stream) {
    const float* x     = (const float*)d_in[0];
    const float* W_ih0 = (const float*)d_in[1];
    const float* W_hh0 = (const float*)d_in[2];
    const float* b_ih0 = (const float*)d_in[3];
    const float* b_hh0 = (const float*)d_in[4];
    const float* W_ih1 = (const float*)d_in[5];
    const float* W_hh1 = (const float*)d_in[6];
    const float* b_ih1 = (const float*)d_in[7];
    const float* b_hh1 = (const float*)d_in[8];
    const float* W_ih2 = (const float*)d_in[9];
    const float* W_hh2 = (const float*)d_in[10];
    const float* b_ih2 = (const float*)d_in[11];
    const float* b_hh2 = (const float*)d_in[12];
    const float* fc_w  = (const float*)d_in[13];
    const float* fc_b  = (const float*)d_in[14];
    float* out = (float*)d_out;

    const size_t PRE_ELEMS = (size_t)2048 * HDIM;   // 409600 floats
    float* P     = (float*)d_ws;
    float* Hbuf  = P + PRE_ELEMS;
    float* Hbuf2 = Hbuf + PRE_ELEMS;

    // ---- layer 0: P = x @ W_ih0^T  (M=2048, K=10000, 32-way K-split) ----
    hipMemsetAsync(P, 0, PRE_ELEMS * sizeof(float), stream);
    gemm_nt_bf16c<<<dim3(16, 32), 512, 0, stream>>>(x, 10000, W_ih0, 10000, P, HDIM, 10000, 10, 1);
    rnn_rec<<<32, 256, 0, stream>>>(P, W_hh0, b_ih0, b_hh0, Hbuf);

    // ---- layer 1: P = H0 @ W_ih1^T  (K=200, single k-block -> plain store) ----
    gemm_nt_bf16c<<<dim3(16, 1), 512, 0, stream>>>(Hbuf, HDIM, W_ih1, HDIM, P, HDIM, HDIM, 7, 0);
    rnn_rec<<<32, 256, 0, stream>>>(P, W_hh1, b_ih1, b_hh1, Hbuf2);

    // ---- layer 2 ----
    gemm_nt_bf16c<<<dim3(16, 1), 512, 0, stream>>>(Hbuf2, HDIM, W_ih2, HDIM, P, HDIM, HDIM, 7, 0);
    rnn_rec<<<32, 256, 0, stream>>>(P, W_hh2, b_ih2, b_hh2, Hbuf);

    // ---- FC head ----
    fc_head<<<1, 64, 0, stream>>>(Hbuf, fc_w, fc_b, out);
}

// Round 6
// 461.962 us; speedup vs baseline: 1.2671x; 1.2671x over previous
//
#include <hip/hip_runtime.h>
#include <hip/hip_bf16.h>

// 3-layer tanh RNN. B=32, T=64, D_IN=10000, H=200, N_CLASSES=2.
//
// R6 design notes:
//  * rec R3..R5 spilled w[200] to scratch (VGPR_Count=120 proved it) ->
//    thread-pair layout: 512 thr, each holds 100 W_hh floats (~130 VGPR, no
//    spill), __shfl_xor(1) combines halves. Fast tanh via __expf.
//  * GEMM R4/R5 was LDS-pipe bound (224 redundant ds_read_b128/CU/kstep +
//    6.3M bank-conflict cyc) -> zero-LDS GEMM: W_ih pre-split ONCE to padded
//    bf16 hi/lo ([208 x Kpad], pad rows/cols zeroed); waves stream A (fp32,
//    reg-split) + B (bf16) straight from global/L2 in fragment layout with
//    register prefetch. No barriers in the K loop at all.
//  * split-bf16 everywhere: v = hi + lo; A*B ~= Ah*Bh + Ah*Bl + Al*Bh (~fp32).

typedef __bf16  bf16x8 __attribute__((ext_vector_type(8)));
typedef float   f32x4  __attribute__((ext_vector_type(4)));

#define HDIM 200
#define BM 128
#define BK 32

// ---------- prologue: fp32 W [HDIM x K] -> padded bf16 hi/lo [208 x Kpad] ----
__global__ void split_weights(const float* __restrict__ W, int K, int Kpad,
                              __bf16* __restrict__ Whi, __bf16* __restrict__ Wlo)
{
    const int gpr = Kpad / 8;             // groups per row
    const int ngroups = 208 * gpr;
    for (int g = blockIdx.x * blockDim.x + threadIdx.x; g < ngroups;
         g += gridDim.x * blockDim.x) {
        const int r  = g / gpr;
        const int c8 = (g - r * gpr) * 8;
        bf16x8 hi, lo;
        if (r < HDIM && c8 < K) {         // K % 8 == 0 -> whole group valid
            const float* p = W + (size_t)r * K + c8;
            float4 x0 = *(const float4*)p, x1 = *(const float4*)(p + 4);
            float v[8] = {x0.x, x0.y, x0.z, x0.w, x1.x, x1.y, x1.z, x1.w};
#pragma unroll
            for (int i = 0; i < 8; ++i) {
                __bf16 h = (__bf16)v[i];
                hi[i] = h; lo[i] = (__bf16)(v[i] - (float)h);
            }
        } else {
#pragma unroll
            for (int i = 0; i < 8; ++i) { hi[i] = (__bf16)0.f; lo[i] = (__bf16)0.f; }
        }
        *(bf16x8*)&Whi[(size_t)r * Kpad + c8] = hi;
        *(bf16x8*)&Wlo[(size_t)r * Kpad + c8] = lo;
    }
}

// ---------- zero-LDS direct GEMM: C[m][n] (+)= sum_k A[m][k]*W[n][k] ----------
// 8 waves = 4 M-groups (32 rows) x 2 N-groups (7/6 nt). Register prefetch.
__global__ __launch_bounds__(512, 1)
void gemm_direct(const float* __restrict__ A, int lda, int K,
                 const __bf16* __restrict__ Whi, const __bf16* __restrict__ Wlo,
                 int Kpad, float* __restrict__ C, int ksteps, int accumulate)
{
    const int tid  = threadIdx.x;
    const int wv   = tid >> 6, lane = tid & 63;
    const int r16  = lane & 15, kg = lane >> 4;     // fragment coords
    const int mwv  = wv & 3,  nwv = wv >> 2;
    const int nt0  = nwv * 7;
    const int ntw  = nwv ? 6 : 7;
    const int m0   = blockIdx.x * BM + mwv * 32;
    const int kbase = blockIdx.y * (ksteps * BK);

    f32x4 acc[2][7];
#pragma unroll
    for (int mi = 0; mi < 2; ++mi)
#pragma unroll
        for (int j = 0; j < 7; ++j) acc[mi][j] = (f32x4)0.f;

    const float*  Ar0 = A + (size_t)(m0 + r16) * lda;
    const float*  Ar1 = A + (size_t)(m0 + 16 + r16) * lda;
    const __bf16* Wh  = Whi + (size_t)(nt0 * 16 + r16) * Kpad;
    const __bf16* Wl  = Wlo + (size_t)(nt0 * 16 + r16) * Kpad;
    const size_t  ntstride = (size_t)16 * Kpad;

    float  a_nx[2][8];
    bf16x8 bh_nx[7], bl_nx[7];

    auto load_k = [&](int ks) {
        const int k = kbase + ks * BK + kg * 8;
        const bool ok = (k < K);              // k%8==0 and K%8==0 -> group-valid
#pragma unroll
        for (int mi = 0; mi < 2; ++mi) {
            if (ok) {
                const float* p = (mi ? Ar1 : Ar0) + k;
                float4 x0 = *(const float4*)p, x1 = *(const float4*)(p + 4);
                a_nx[mi][0]=x0.x; a_nx[mi][1]=x0.y; a_nx[mi][2]=x0.z; a_nx[mi][3]=x0.w;
                a_nx[mi][4]=x1.x; a_nx[mi][5]=x1.y; a_nx[mi][6]=x1.z; a_nx[mi][7]=x1.w;
            } else {
#pragma unroll
                for (int i = 0; i < 8; ++i) a_nx[mi][i] = 0.f;
            }
        }
#pragma unroll
        for (int j = 0; j < 7; ++j) {
            if (j < ntw) {                    // rows/cols padded: always in-bounds
                bh_nx[j] = *(const bf16x8*)&Wh[j * ntstride + k];
                bl_nx[j] = *(const bf16x8*)&Wl[j * ntstride + k];
            }
        }
    };

    load_k(0);

    for (int ks = 0; ks < ksteps; ++ks) {
        float  a_c[2][8];
        bf16x8 bh_c[7], bl_c[7];
#pragma unroll
        for (int mi = 0; mi < 2; ++mi)
#pragma unroll
            for (int i = 0; i < 8; ++i) a_c[mi][i] = a_nx[mi][i];
#pragma unroll
        for (int j = 0; j < 7; ++j) { bh_c[j] = bh_nx[j]; bl_c[j] = bl_nx[j]; }

        if (ks + 1 < ksteps) load_k(ks + 1);   // prefetch overlaps MFMA below

        bf16x8 ah[2], al[2];
#pragma unroll
        for (int mi = 0; mi < 2; ++mi)
#pragma unroll
            for (int i = 0; i < 8; ++i) {
                __bf16 h = (__bf16)a_c[mi][i];
                ah[mi][i] = h; al[mi][i] = (__bf16)(a_c[mi][i] - (float)h);
            }
#pragma unroll
        for (int j = 0; j < 7; ++j) {
            if (j < ntw) {
#pragma unroll
                for (int mi = 0; mi < 2; ++mi) {
                    acc[mi][j] = __builtin_amdgcn_mfma_f32_16x16x32_bf16(al[mi], bh_c[j], acc[mi][j], 0, 0, 0);
                    acc[mi][j] = __builtin_amdgcn_mfma_f32_16x16x32_bf16(ah[mi], bl_c[j], acc[mi][j], 0, 0, 0);
                    acc[mi][j] = __builtin_amdgcn_mfma_f32_16x16x32_bf16(ah[mi], bh_c[j], acc[mi][j], 0, 0, 0);
                }
            }
        }
    }

    // epilogue: C/D layout col=lane&15, row=(lane>>4)*4+reg
#pragma unroll
    for (int mi = 0; mi < 2; ++mi) {
        const int rbase = m0 + mi * 16 + kg * 4;
#pragma unroll
        for (int j = 0; j < 7; ++j) {
            if (j < ntw) {
                const int n = (nt0 + j) * 16 + r16;
                if (n < HDIM) {
                    if (accumulate) {
#pragma unroll
                        for (int r = 0; r < 4; ++r)
                            atomicAdd(&C[(size_t)(rbase + r) * HDIM + n], acc[mi][j][r]);
                    } else {
#pragma unroll
                        for (int r = 0; r < 4; ++r)
                            C[(size_t)(rbase + r) * HDIM + n] = acc[mi][j][r];
                    }
                }
            }
        }
    }
}

__device__ __forceinline__ float fast_tanh(float x) {
    float e = __expf(-2.f * fabsf(x));        // e in (0,1]: no overflow
    float r = (1.f - e) / (1.f + e);
    return copysignf(r, x);
}

// ---------- recurrence: 1 block / batch elem; thread pair (n, half) ----------
// Each thread holds 100 W_hh floats in VGPRs (no spill); halves combined via
// __shfl_xor(1). h double-buffered in LDS (broadcast reads); 1 barrier/step.
__global__ __launch_bounds__(512, 1)
void rnn_rec(const float* __restrict__ pre,   // [32][64][200] (GEMM only)
             const float* __restrict__ Whh,   // [200][200]
             const float* __restrict__ bih,
             const float* __restrict__ bhh,
             float* __restrict__ Hout)        // [32][64][200]
{
    const int b    = blockIdx.x;
    const int tid  = threadIdx.x;
    const int n    = tid >> 1;        // 0..255 (active n<200)
    const int half = tid & 1;
    const bool active = (n < HDIM);
    const int nc   = active ? n : (HDIM - 1);   // clamped for always-valid loads

    __shared__ float h[2][HDIM];
    __shared__ float bias[HDIM];

    float w[100];
    {
        const float* wr = Whh + (size_t)nc * HDIM + half * 100;
#pragma unroll
        for (int i = 0; i < 25; ++i) {
            float4 v = *(const float4*)(wr + i * 4);
            w[i * 4 + 0] = v.x; w[i * 4 + 1] = v.y;
            w[i * 4 + 2] = v.z; w[i * 4 + 3] = v.w;
        }
    }
    if (tid < HDIM) { bias[tid] = bih[tid] + bhh[tid]; h[0][tid] = 0.f; }
    __syncthreads();

    const float* preb = pre + (size_t)b * 64 * HDIM;

    for (int t = 0; t < 64; ++t) {
        float p = preb[t * HDIM + nc];               // issued early, used late
        const float* hc = &h[t & 1][half * 100];
        float a0 = 0.f, a1 = 0.f, a2 = 0.f, a3 = 0.f;
#pragma unroll
        for (int i = 0; i < 25; ++i) {
            float4 hv = *(const float4*)&hc[i * 4];  // 2-addr broadcast read
            a0 += w[i * 4 + 0] * hv.x;
            a1 += w[i * 4 + 1] * hv.y;
            a2 += w[i * 4 + 2] * hv.z;
            a3 += w[i * 4 + 3] * hv.w;
        }
        float s = (a0 + a1) + (a2 + a3);
        s += __shfl_xor(s, 1);                       // combine the two halves
        if (active && half == 0) {
            float v = fast_tanh(s + p + bias[n]);
            h[(t + 1) & 1][n] = v;
            Hout[((size_t)b * 64 + t) * HDIM + n] = v;
        }
        __syncthreads();
    }
}

// Trivially-correct FC head (R3-proven).
__global__ void fc_head(const float* __restrict__ Hlast_base, // [32][64][200]
                        const float* __restrict__ fcw,        // [2][200]
                        const float* __restrict__ fcb,        // [2]
                        float* __restrict__ out)              // [32][2]
{
    const int i = threadIdx.x;   // 0..63
    if (i >= 64) return;
    const int b   = i >> 1;
    const int cls = i & 1;
    const float* hp = Hlast_base + ((size_t)b * 64 + 63) * HDIM;
    const float* fw = fcw + cls * HDIM;
    float s = fcb[cls];
    for (int j = 0; j < HDIM; ++j) s += hp[j] * fw[j];
    out[b * 2 + cls] = s;
}

extern "C" void kernel_launch(void* const* d_in, const int* in_sizes, int n_in,
                              void* d_out, int out_size, void* d_ws, size_t ws_size,
                              hipStream_t stream) {
    const float* x     = (const float*)d_in[0];
    const float* W_ih0 = (const float*)d_in[1];
    const float* W_hh0 = (const float*)d_in[2];
    const float* b_ih0 = (const float*)d_in[3];
    const float* b_hh0 = (const float*)d_in[4];
    const float* W_ih1 = (const float*)d_in[5];
    const float* W_hh1 = (const float*)d_in[6];
    const float* b_ih1 = (const float*)d_in[7];
    const float* b_hh1 = (const float*)d_in[8];
    const float* W_ih2 = (const float*)d_in[9];
    const float* W_hh2 = (const float*)d_in[10];
    const float* b_ih2 = (const float*)d_in[11];
    const float* b_hh2 = (const float*)d_in[12];
    const float* fc_w  = (const float*)d_in[13];
    const float* fc_b  = (const float*)d_in[14];
    float* out = (float*)d_out;

    // Kpad covers the k-grid exactly: L0: 16 blocks x 20 ksteps x 32 = 10240;
    // L1/2: 7 x 32 = 224. Padding rows/cols are zero-filled by split_weights.
    const int KP0 = 10240, KP12 = 224;

    const size_t PRE_ELEMS = (size_t)2048 * HDIM;   // 409600 floats
    float* P     = (float*)d_ws;
    float* Hbuf  = P + PRE_ELEMS;
    float* Hbuf2 = Hbuf + PRE_ELEMS;
    float* wsf   = Hbuf2 + PRE_ELEMS;
    __bf16* W0hi = (__bf16*)wsf;                    // 208*10240 bf16 each
    __bf16* W0lo = W0hi + (size_t)208 * KP0;
    __bf16* W1hi = W0lo + (size_t)208 * KP0;        // 208*224 bf16 each
    __bf16* W1lo = W1hi + (size_t)208 * KP12;
    __bf16* W2hi = W1lo + (size_t)208 * KP12;
    __bf16* W2lo = W2hi + (size_t)208 * KP12;

    // ---- prologue: pre-split all W_ih (pads zeroed every call) ----
    split_weights<<<512, 256, 0, stream>>>(W_ih0, 10000, KP0, W0hi, W0lo);
    split_weights<<<32, 256, 0, stream>>>(W_ih1, HDIM, KP12, W1hi, W1lo);
    split_weights<<<32, 256, 0, stream>>>(W_ih2, HDIM, KP12, W2hi, W2lo);

    // ---- layer 0: P = x @ W_ih0^T  (M=2048, K=10000, 16-way k-split) ----
    hipMemsetAsync(P, 0, PRE_ELEMS * sizeof(float), stream);
    gemm_direct<<<dim3(16, 16), 512, 0, stream>>>(x, 10000, 10000, W0hi, W0lo, KP0, P, 20, 1);
    rnn_rec<<<32, 512, 0, stream>>>(P, W_hh0, b_ih0, b_hh0, Hbuf);

    // ---- layer 1 ----
    gemm_direct<<<dim3(16, 1), 512, 0, stream>>>(Hbuf, HDIM, HDIM, W1hi, W1lo, KP12, P, 7, 0);
    rnn_rec<<<32, 512, 0, stream>>>(P, W_hh1, b_ih1, b_hh1, Hbuf2);

    // ---- layer 2 ----
    gemm_direct<<<dim3(16, 1), 512, 0, stream>>>(Hbuf2, HDIM, HDIM, W2hi, W2lo, KP12, P, 7, 0);
    rnn_rec<<<32, 512, 0, stream>>>(P, W_hh2, b_ih2, b_hh2, Hbuf);

    // ---- FC head ----
    fc_head<<<1, 64, 0, stream>>>(Hbuf, fc_w, fc_b, out);
}

// Round 7
// 332.715 us; speedup vs baseline: 1.7593x; 1.3885x over previous
//
#include <hip/hip_runtime.h>
#include <hip/hip_bf16.h>

// 3-layer tanh RNN. B=32, T=64, D_IN=10000, H=200, N_CLASSES=2.
//
// R7:
//  * gemm: m97-style pipeline. W pre-packed (bf16 hi/lo, per-32-k-chunk
//    contiguous [208x32] hi then lo) -> global_load_lds(16B) staging; A
//    split in-kernel; double-buffered LDS, ONE barrier/kstep; K-split 16
//    into atomic-free partial buffers + reduce kernel.
//  * rec: LDS-broadcast traffic was the binder (200KB/step). Register-block
//    4 outputs/thread: w[80] (no spill; w[200] spilled in R3), 10-way k-split,
//    partial reduce in LDS. Two barriers/step.
//  * split-bf16 3-term everywhere: ~fp32 accuracy at bf16 MFMA rate.

typedef __bf16  bf16x8 __attribute__((ext_vector_type(8)));
typedef float   f32x4  __attribute__((ext_vector_type(4)));

#define HDIM 200
#define BM 128
#define CHUNK_B 26624   // bytes per packed k-chunk: [208x32] hi (13312) + lo
#define MFMA(a, b, c) __builtin_amdgcn_mfma_f32_16x16x32_bf16(a, b, c, 0, 0, 0)

__device__ __forceinline__ void glds16(const void* g, void* l) {
    __builtin_amdgcn_global_load_lds(
        (const __attribute__((address_space(1))) unsigned int*)g,
        (__attribute__((address_space(3))) unsigned int*)l, 16, 0, 0);
}

// ---- pack W [HDIM x K] fp32 -> chunks: [kc][208 rows x 32 k] bf16 hi, lo ----
__global__ void pack_w(const float* __restrict__ W, int K, int nkc,
                       __bf16* __restrict__ out)
{
    const int total = nkc * 1664;            // 16B-chunks per k-chunk = 1664
    for (int g = blockIdx.x * blockDim.x + threadIdx.x; g < total;
         g += gridDim.x * blockDim.x) {
        const int kc = g / 1664;
        const int o  = g - kc * 1664;
        const int isLo = (o >= 832);
        const int o2 = isLo ? o - 832 : o;
        const int r  = o2 >> 2;              // 0..207
        const int k  = kc * 32 + (o2 & 3) * 8;
        bf16x8 v;
        if (r < HDIM && k < K) {             // K % 8 == 0
            const float* p = W + (size_t)r * K + k;
            float4 a = *(const float4*)p, b = *(const float4*)(p + 4);
            float f[8] = {a.x, a.y, a.z, a.w, b.x, b.y, b.z, b.w};
#pragma unroll
            for (int i = 0; i < 8; ++i) {
                __bf16 h = (__bf16)f[i];
                v[i] = isLo ? (__bf16)(f[i] - (float)h) : h;
            }
        } else {
#pragma unroll
            for (int i = 0; i < 8; ++i) v[i] = (__bf16)0.f;
        }
        *(bf16x8*)&out[(size_t)g * 8] = v;
    }
}

// ---- pipelined GEMM: C[m][n] = sum_k A[m][k]*W[n][k] over this block's k ----
// 8 waves = 4 M-groups (2 Mtiles) x 2 N-groups (7/6 nt). One barrier/kstep.
__global__ __launch_bounds__(512, 1)
void gemm_pipe(const float* __restrict__ A, int lda, int K,
               const __bf16* __restrict__ Bpack,
               float* __restrict__ Cbase, int per_split, int ksteps)
{
    __shared__ alignas(16) __bf16 Ab[2][8192];    // [hi 4096 | lo 4096] (128x32)
    __shared__ alignas(16) __bf16 Bb[2][13312];   // [hi 6656 | lo 6656] (208x32)

    const int tid = threadIdx.x;
    const int kc0 = blockIdx.y * ksteps;
    const int m0  = blockIdx.x * BM;
    float* __restrict__ C = Cbase + (size_t)blockIdx.y * per_split;

    const int wv = tid >> 6, lane = tid & 63;
    const int r16 = lane & 15, kg = lane >> 4;
    const int mg = wv & 3, ng = wv >> 2;
    const int nt0 = ng * 7, ntw = ng ? 6 : 7;

    const int a_row = tid >> 2;          // 0..127
    const int a_q   = tid & 3;           // 8-float column group
    const float* Arow = A + (size_t)(m0 + a_row) * lda + a_q * 8;

    f32x4 acc[2][7];
#pragma unroll
    for (int mi = 0; mi < 2; ++mi)
#pragma unroll
        for (int j = 0; j < 7; ++j) acc[mi][j] = (f32x4)0.f;

    float av[8];
    auto loadA = [&](int ks) {
        const int kb = (kc0 + ks) * 32;
        if (kb + a_q * 8 < K) {          // 8-granular, K % 8 == 0
            const float* p = Arow + kb;
            float4 x0 = *(const float4*)p, x1 = *(const float4*)(p + 4);
            av[0]=x0.x; av[1]=x0.y; av[2]=x0.z; av[3]=x0.w;
            av[4]=x1.x; av[5]=x1.y; av[6]=x1.z; av[7]=x1.w;
        } else {
#pragma unroll
            for (int i = 0; i < 8; ++i) av[i] = 0.f;
        }
    };
    auto issueB = [&](int ks, int buf) {
        const char* src = (const char*)Bpack + (size_t)(kc0 + ks) * CHUNK_B;
        char* dst = (char*)&Bb[buf][0];
#pragma unroll
        for (int r = 0; r < 3; ++r)
            glds16(src + (r * 512 + tid) * 16, dst + (r * 512 + tid) * 16);
        if (tid < 128)
            glds16(src + (1536 + tid) * 16, dst + (1536 + tid) * 16);
    };

    loadA(0);
    issueB(0, 0);

    for (int ks = 0; ks < ksteps; ++ks) {
        const int cur = ks & 1, nxt = cur ^ 1;
        // commit A regs -> LDS hi/lo  (Ab[cur] last read in iter ks-2: safe)
        bf16x8 th, tl;
#pragma unroll
        for (int i = 0; i < 8; ++i) {
            __bf16 h = (__bf16)av[i];
            th[i] = h; tl[i] = (__bf16)(av[i] - (float)h);
        }
        *(bf16x8*)&Ab[cur][a_row * 32 + a_q * 8]        = th;
        *(bf16x8*)&Ab[cur][4096 + a_row * 32 + a_q * 8] = tl;
        __syncthreads();   // drains glds B(ks)->Bb[cur] + A writes (vmcnt+lgkm)
        if (ks + 1 < ksteps) { issueB(ks + 1, nxt); loadA(ks + 1); }

        const int ao0 = (mg * 32 + r16) * 32 + kg * 8;
        const int ao1 = ao0 + 16 * 32;
        bf16x8 ah0 = *(const bf16x8*)&Ab[cur][ao0];
        bf16x8 al0 = *(const bf16x8*)&Ab[cur][4096 + ao0];
        bf16x8 ah1 = *(const bf16x8*)&Ab[cur][ao1];
        bf16x8 al1 = *(const bf16x8*)&Ab[cur][4096 + ao1];
#pragma unroll
        for (int j = 0; j < 7; ++j) {
            if (j < ntw) {
                const int bo = ((nt0 + j) * 16 + r16) * 32 + kg * 8;
                bf16x8 bh = *(const bf16x8*)&Bb[cur][bo];
                bf16x8 bl = *(const bf16x8*)&Bb[cur][6656 + bo];
                acc[0][j] = MFMA(al0, bh, acc[0][j]);
                acc[0][j] = MFMA(ah0, bl, acc[0][j]);
                acc[0][j] = MFMA(ah0, bh, acc[0][j]);
                acc[1][j] = MFMA(al1, bh, acc[1][j]);
                acc[1][j] = MFMA(ah1, bl, acc[1][j]);
                acc[1][j] = MFMA(ah1, bh, acc[1][j]);
            }
        }
    }

    // epilogue: C/D layout col=lane&15, row=(lane>>4)*4+reg; plain stores
#pragma unroll
    for (int mi = 0; mi < 2; ++mi) {
        const int rb = m0 + (mg * 2 + mi) * 16 + kg * 4;
#pragma unroll
        for (int j = 0; j < 7; ++j) {
            if (j < ntw) {
                const int n = (nt0 + j) * 16 + r16;
                if (n < HDIM)
#pragma unroll
                    for (int r = 0; r < 4; ++r)
                        C[(size_t)(rb + r) * HDIM + n] = acc[mi][j][r];
            }
        }
    }
}

// ---- sum 16 k-split partials ----
__global__ void reduce_parts(const float* __restrict__ Pp, float* __restrict__ P)
{
    const int i = blockIdx.x * blockDim.x + threadIdx.x;   // float4 index
    if (i < 102400) {
        float4 s = ((const float4*)Pp)[i];
#pragma unroll
        for (int r = 1; r < 16; ++r) {
            float4 v = ((const float4*)Pp)[(size_t)r * 102400 + i];
            s.x += v.x; s.y += v.y; s.z += v.z; s.w += v.w;
        }
        ((float4*)P)[i] = s;
    }
}

__device__ __forceinline__ float fast_tanh(float x) {
    float e = __expf(-2.f * fabsf(x));
    float r = (1.f - e) / (1.f + e);
    return copysignf(r, x);
}

// ---- recurrence: 1 block/batch; thread owns 4 n x 20 k; w[80] in VGPRs ----
__global__ __launch_bounds__(512, 1)
void rnn_rec(const float* __restrict__ pre,   // [32][64][200] (GEMM only)
             const float* __restrict__ Whh,   // [200][200]
             const float* __restrict__ bih,
             const float* __restrict__ bhh,
             float* __restrict__ Hout)        // [32][64][200]
{
    const int b   = blockIdx.x;
    const int tid = threadIdx.x;

    __shared__ float preS[64 * HDIM];          // 51.2 KB
    __shared__ float h[HDIM];
    __shared__ float bias[HDIM];
    __shared__ float part[10][HDIM];           // 8 KB

    {   // stage pre slab (coalesced)
        const float4* ps = (const float4*)(pre + (size_t)b * 64 * HDIM);
        float4* pd = (float4*)preS;
        for (int i = tid; i < 3200; i += 512) pd[i] = ps[i];
    }

    const bool act = tid < 500;
    const int g  = tid / 10;            // n-group 0..49
    const int s  = tid - g * 10;        // k-slice 0..9
    const int n0 = g * 4;
    const int k0 = s * 20;

    float w[80];
    if (act) {
#pragma unroll
        for (int j = 0; j < 4; ++j) {
            const float* wr = Whh + (size_t)(n0 + j) * HDIM + k0;
#pragma unroll
            for (int i = 0; i < 5; ++i) {
                float4 v = *(const float4*)(wr + i * 4);
                w[j * 20 + i * 4 + 0] = v.x; w[j * 20 + i * 4 + 1] = v.y;
                w[j * 20 + i * 4 + 2] = v.z; w[j * 20 + i * 4 + 3] = v.w;
            }
        }
    }
    if (tid < HDIM) { bias[tid] = bih[tid] + bhh[tid]; h[tid] = 0.f; }
    __syncthreads();

    for (int t = 0; t < 64; ++t) {
        if (act) {
            float a0 = 0.f, a1 = 0.f, a2 = 0.f, a3 = 0.f;
#pragma unroll
            for (int i = 0; i < 5; ++i) {
                float4 hv = *(const float4*)&h[k0 + i * 4];
                a0 += w[ 0 + i*4]*hv.x + w[ 1 + i*4]*hv.y + w[ 2 + i*4]*hv.z + w[ 3 + i*4]*hv.w;
                a1 += w[20 + i*4]*hv.x + w[21 + i*4]*hv.y + w[22 + i*4]*hv.z + w[23 + i*4]*hv.w;
                a2 += w[40 + i*4]*hv.x + w[41 + i*4]*hv.y + w[42 + i*4]*hv.z + w[43 + i*4]*hv.w;
                a3 += w[60 + i*4]*hv.x + w[61 + i*4]*hv.y + w[62 + i*4]*hv.z + w[63 + i*4]*hv.w;
            }
            float4 pv = make_float4(a0, a1, a2, a3);
            *(float4*)&part[s][n0] = pv;
        }
        __syncthreads();
        if (tid < HDIM) {
            float sum = part[0][tid];
#pragma unroll
            for (int r = 1; r < 10; ++r) sum += part[r][tid];
            float v = fast_tanh(sum + preS[t * HDIM + tid] + bias[tid]);
            h[tid] = v;
            Hout[((size_t)b * 64 + t) * HDIM + tid] = v;
        }
        __syncthreads();
    }
}

// Wrong-index bug note: w[j*20 + i*4 + c] is written; the FMA block above
// indexes w[c + i*4] for j=0 etc. -- offsets 0/20/40/60 match j*20. OK.

// ---- trivially-correct FC head ----
__global__ void fc_head(const float* __restrict__ Hlast_base,
                        const float* __restrict__ fcw,
                        const float* __restrict__ fcb,
                        float* __restrict__ out)
{
    const int i = threadIdx.x;
    if (i >= 64) return;
    const int b = i >> 1, cls = i & 1;
    const float* hp = Hlast_base + ((size_t)b * 64 + 63) * HDIM;
    const float* fw = fcw + cls * HDIM;
    float s = fcb[cls];
    for (int j = 0; j < HDIM; ++j) s += hp[j] * fw[j];
    out[b * 2 + cls] = s;
}

extern "C" void kernel_launch(void* const* d_in, const int* in_sizes, int n_in,
                              void* d_out, int out_size, void* d_ws, size_t ws_size,
                              hipStream_t stream) {
    const float* x     = (const float*)d_in[0];
    const float* W_ih0 = (const float*)d_in[1];
    const float* W_hh0 = (const float*)d_in[2];
    const float* b_ih0 = (const float*)d_in[3];
    const float* b_hh0 = (const float*)d_in[4];
    const float* W_ih1 = (const float*)d_in[5];
    const float* W_hh1 = (const float*)d_in[6];
    const float* b_ih1 = (const float*)d_in[7];
    const float* b_hh1 = (const float*)d_in[8];
    const float* W_ih2 = (const float*)d_in[9];
    const float* W_hh2 = (const float*)d_in[10];
    const float* b_ih2 = (const float*)d_in[11];
    const float* b_hh2 = (const float*)d_in[12];
    const float* fc_w  = (const float*)d_in[13];
    const float* fc_b  = (const float*)d_in[14];
    float* out = (float*)d_out;

    const size_t PE = (size_t)2048 * HDIM;          // 409600
    float* P     = (float*)d_ws;
    float* Hbuf  = P + PE;
    float* Hbuf2 = Hbuf + PE;
    float* Ppart = Hbuf2 + PE;                      // 16 x 409600
    __bf16* W0p  = (__bf16*)(Ppart + 16 * PE);      // 320 chunks x 13312 bf16
    __bf16* W1p  = W0p + (size_t)320 * 13312;       // 7 chunks
    __bf16* W2p  = W1p + (size_t)7 * 13312;
    // total ws: ~40.0 MB

    // ---- prologue: pack weights ----
    pack_w<<<1024, 256, 0, stream>>>(W_ih0, 10000, 320, W0p);
    pack_w<<<46, 256, 0, stream>>>(W_ih1, HDIM, 7, W1p);
    pack_w<<<46, 256, 0, stream>>>(W_ih2, HDIM, 7, W2p);

    // ---- layer 0: K=10000, 16-way k-split (20 ksteps each), partials ----
    gemm_pipe<<<dim3(16, 16), 512, 0, stream>>>(x, 10000, 10000, W0p, Ppart, (int)PE, 20);
    reduce_parts<<<400, 256, 0, stream>>>(Ppart, P);
    rnn_rec<<<32, 512, 0, stream>>>(P, W_hh0, b_ih0, b_hh0, Hbuf);

    // ---- layer 1: K=200, single split, direct store ----
    gemm_pipe<<<dim3(16, 1), 512, 0, stream>>>(Hbuf, HDIM, HDIM, W1p, P, (int)PE, 7);
    rnn_rec<<<32, 512, 0, stream>>>(P, W_hh1, b_ih1, b_hh1, Hbuf2);

    // ---- layer 2 ----
    gemm_pipe<<<dim3(16, 1), 512, 0, stream>>>(Hbuf2, HDIM, HDIM, W2p, P, (int)PE, 7);
    rnn_rec<<<32, 512, 0, stream>>>(P, W_hh2, b_ih2, b_hh2, Hbuf);

    // ---- FC head ----
    fc_head<<<1, 64, 0, stream>>>(Hbuf, fc_w, fc_b, out);
}